// Round 2
// baseline (1202.493 us; speedup 1.0000x reference)
//
#include <hip/hip_runtime.h>
#include <math.h>

namespace {

constexpr int kB = 2, kS = 2048, kD = 768, kH = 12, kHD = 64, kF = 128, kBH = kB * kH;
constexpr float kScale = 0.125f;  // 1/sqrt(64)

__device__ __forceinline__ void fma16(const float4& a4, const float4& b4, float (&acc)[4][4]) {
    const float a[4] = {a4.x, a4.y, a4.z, a4.w};
    const float b[4] = {b4.x, b4.y, b4.z, b4.w};
    #pragma unroll
    for (int i = 0; i < 4; ++i)
        #pragma unroll
        for (int j = 0; j < 4; ++j)
            acc[i][j] = fmaf(a[i], b[j], acc[i][j]);
}

// ---------------- QKV projection: q/k/v[b,h,s,d] = h @ W.T + b ----------------
__global__ __launch_bounds__(256) void qkv_proj_kernel(
    const float* __restrict__ hidden,
    const float* __restrict__ Wq, const float* __restrict__ bq,
    const float* __restrict__ Wk, const float* __restrict__ bk,
    const float* __restrict__ Wv, const float* __restrict__ bv,
    float* __restrict__ qd, float* __restrict__ kd, float* __restrict__ vd)
{
    const int which = blockIdx.z;
    const float* __restrict__ W    = (which == 0) ? Wq : (which == 1) ? Wk : Wv;
    const float* __restrict__ bias = (which == 0) ? bq : (which == 1) ? bk : bv;
    float* __restrict__ dst        = (which == 0) ? qd : (which == 1) ? kd : vd;

    const int m0 = blockIdx.x * 64;
    const int n0 = blockIdx.y * 64;
    const int t = threadIdx.x;
    const int tx = t & 15, ty = t >> 4;
    const int lrow = t >> 2;
    const int lc4 = (t & 3) * 4;

    __shared__ float At[16][68];  // At[kk][row]
    __shared__ float Wt[16][68];  // Wt[kk][col]

    float acc[4][4] = {};

    for (int k0 = 0; k0 < kD; k0 += 16) {
        float4 av = *(const float4*)&hidden[(size_t)(m0 + lrow) * kD + k0 + lc4];
        float4 wv = *(const float4*)&W[(size_t)(n0 + lrow) * kD + k0 + lc4];
        At[lc4 + 0][lrow] = av.x; At[lc4 + 1][lrow] = av.y;
        At[lc4 + 2][lrow] = av.z; At[lc4 + 3][lrow] = av.w;
        Wt[lc4 + 0][lrow] = wv.x; Wt[lc4 + 1][lrow] = wv.y;
        Wt[lc4 + 2][lrow] = wv.z; Wt[lc4 + 3][lrow] = wv.w;
        __syncthreads();
        #pragma unroll
        for (int kk = 0; kk < 16; ++kk) {
            float4 a4 = *(const float4*)&At[kk][ty * 4];
            float4 b4 = *(const float4*)&Wt[kk][tx * 4];
            fma16(a4, b4, acc);
        }
        __syncthreads();
    }

    const int hh = n0 >> 6;  // tile spans exactly one head
    float4 bv4 = *(const float4*)&bias[n0 + tx * 4];
    const float badd[4] = {bv4.x, bv4.y, bv4.z, bv4.w};
    #pragma unroll
    for (int i = 0; i < 4; ++i) {
        const int m = m0 + ty * 4 + i;
        const int b_ = m >> 11, s_ = m & (kS - 1);
        float4 o;
        o.x = acc[i][0] + badd[0]; o.y = acc[i][1] + badd[1];
        o.z = acc[i][2] + badd[2]; o.w = acc[i][3] + badd[3];
        *(float4*)&dst[((size_t)(b_ * kH + hh) * kS + s_) * kHD + tx * 4] = o;
    }
}

// ---------------- hedgehog feature maps: [exp(y), exp(-y)], y = x @ Wf.T + bf ----------------
__global__ __launch_bounds__(256) void featmap_kernel(
    const float* __restrict__ q, const float* __restrict__ k,
    const float* __restrict__ Wfq, const float* __restrict__ bfq,
    const float* __restrict__ Wfk, const float* __restrict__ bfk,
    float* __restrict__ fq, float* __restrict__ fk)
{
    const int zi = blockIdx.y;
    const float* __restrict__ src = zi == 0 ? q : k;
    const float* __restrict__ Wf  = zi == 0 ? Wfq : Wfk;
    const float* __restrict__ bf  = zi == 0 ? bfq : bfk;
    float* __restrict__ dst       = zi == 0 ? fq : fk;

    const int row0 = blockIdx.x * 64;
    const int t = threadIdx.x;
    const int lane = t & 63, w = t >> 6;
    const int lrow = t >> 2, lc = (t & 3) * 16;

    __shared__ float Wl[64][65];
    __shared__ float ql[64][64];

    #pragma unroll
    for (int c = 0; c < 16; c += 4) {
        float4 u = *(const float4*)&Wf[(size_t)lrow * 64 + lc + c];
        Wl[lrow][lc + c + 0] = u.x; Wl[lrow][lc + c + 1] = u.y;
        Wl[lrow][lc + c + 2] = u.z; Wl[lrow][lc + c + 3] = u.w;
        *(float4*)&ql[lrow][lc + c] =
            *(const float4*)&src[(size_t)(row0 + lrow) * kHD + lc + c];
    }
    __syncthreads();

    float wreg[64];
    #pragma unroll
    for (int d = 0; d < 64; ++d) wreg[d] = Wl[lane][d];
    const float bfv = bf[lane];

    for (int rl = 0; rl < 16; ++rl) {
        const int r = w * 16 + rl;
        float y = bfv;
        #pragma unroll
        for (int d4 = 0; d4 < 64; d4 += 4) {
            float4 qv = *(const float4*)&ql[r][d4];
            y = fmaf(qv.x, wreg[d4 + 0], y);
            y = fmaf(qv.y, wreg[d4 + 1], y);
            y = fmaf(qv.z, wreg[d4 + 2], y);
            y = fmaf(qv.w, wreg[d4 + 3], y);
        }
        const size_t base = (size_t)(row0 + r) * kF;
        dst[base + lane]      = __expf(y);
        dst[base + 64 + lane] = __expf(-y);
    }
}

// ---------------- fk column sums (denominator of pred_attns) ----------------
__global__ __launch_bounds__(128) void fksum_part_kernel(
    const float* __restrict__ fk, float* __restrict__ part)
{
    const int bh = blockIdx.x, g = blockIdx.y, e = threadIdx.x;
    float acc = 0.f;
    const float* p = fk + ((size_t)bh * kS + g * 128) * kF + e;
    for (int n = 0; n < 128; ++n) acc += p[(size_t)n * kF];
    part[((size_t)bh * 16 + g) * kF + e] = acc;
}

__global__ __launch_bounds__(128) void fksum_red_kernel(
    const float* __restrict__ part, float* __restrict__ fksum)
{
    const int bh = blockIdx.x, e = threadIdx.x;
    float acc = 0.f;
    for (int g = 0; g < 16; ++g) acc += part[((size_t)bh * 16 + g) * kF + e];
    fksum[bh * kF + e] = acc;
}

// ---------------- softmax attention: true_attns + outputs ----------------
__global__ __launch_bounds__(256) void true_attn_kernel(
    const float* __restrict__ q, const float* __restrict__ k, const float* __restrict__ v,
    float* __restrict__ out0, float* __restrict__ out2)
{
    const int bh = blockIdx.y;
    const int m0 = blockIdx.x * 64;
    const int t = threadIdx.x;
    const int tx = t & 15, ty = t >> 4;
    const int lrow = t >> 2, lc = (t & 3) * 16;

    __shared__ float qt[64][68];  // qt[kk][row], pre-scaled
    __shared__ float kt[64][68];  // kt[kk][col]; reused as p[n][row] in pass 2
    __shared__ float vn[64][68];  // vn[n][d] natural

    const float* __restrict__ qb = q + (size_t)bh * kS * kHD;
    const float* __restrict__ kb = k + (size_t)bh * kS * kHD;
    const float* __restrict__ vb = v + (size_t)bh * kS * kHD;

    #pragma unroll
    for (int c = 0; c < 16; c += 4) {
        float4 u = *(const float4*)&qb[(size_t)(m0 + lrow) * kHD + lc + c];
        qt[lc + c + 0][lrow] = u.x * kScale;
        qt[lc + c + 1][lrow] = u.y * kScale;
        qt[lc + c + 2][lrow] = u.z * kScale;
        qt[lc + c + 3][lrow] = u.w * kScale;
    }

    float m_[4], l_[4];
    #pragma unroll
    for (int i = 0; i < 4; ++i) { m_[i] = -INFINITY; l_[i] = 0.f; }

    // ---- pass 1: online (max, sumexp) ----
    for (int n0 = 0; n0 < kS; n0 += 64) {
        #pragma unroll
        for (int c = 0; c < 16; c += 4) {
            float4 u = *(const float4*)&kb[(size_t)(n0 + lrow) * kHD + lc + c];
            kt[lc + c + 0][lrow] = u.x; kt[lc + c + 1][lrow] = u.y;
            kt[lc + c + 2][lrow] = u.z; kt[lc + c + 3][lrow] = u.w;
        }
        __syncthreads();
        float s[4][4] = {};
        #pragma unroll 16
        for (int kk = 0; kk < 64; ++kk) {
            float4 a4 = *(const float4*)&qt[kk][ty * 4];
            float4 b4 = *(const float4*)&kt[kk][tx * 4];
            fma16(a4, b4, s);
        }
        #pragma unroll
        for (int i = 0; i < 4; ++i) {
            float tm = fmaxf(fmaxf(s[i][0], s[i][1]), fmaxf(s[i][2], s[i][3]));
            #pragma unroll
            for (int off = 8; off >= 1; off >>= 1) tm = fmaxf(tm, __shfl_xor(tm, off, 16));
            const float mn = fmaxf(m_[i], tm);
            float ts = __expf(s[i][0] - mn) + __expf(s[i][1] - mn)
                     + __expf(s[i][2] - mn) + __expf(s[i][3] - mn);
            #pragma unroll
            for (int off = 8; off >= 1; off >>= 1) ts += __shfl_xor(ts, off, 16);
            l_[i] = l_[i] * __expf(m_[i] - mn) + ts;
            m_[i] = mn;
        }
        __syncthreads();
    }

    float inv_[4];
    #pragma unroll
    for (int i = 0; i < 4; ++i) inv_[i] = 1.f / l_[i];
    float acc[4][4] = {};
    const int b_ = bh / kH, h_ = bh % kH;

    // ---- pass 2: write probs + accumulate PV ----
    for (int n0 = 0; n0 < kS; n0 += 64) {
        __syncthreads();  // previous PV reads done before overwriting tiles
        #pragma unroll
        for (int c = 0; c < 16; c += 4) {
            float4 u = *(const float4*)&kb[(size_t)(n0 + lrow) * kHD + lc + c];
            kt[lc + c + 0][lrow] = u.x; kt[lc + c + 1][lrow] = u.y;
            kt[lc + c + 2][lrow] = u.z; kt[lc + c + 3][lrow] = u.w;
            *(float4*)&vn[lrow][lc + c] =
                *(const float4*)&vb[(size_t)(n0 + lrow) * kHD + lc + c];
        }
        __syncthreads();
        float s[4][4] = {};
        #pragma unroll 16
        for (int kk = 0; kk < 64; ++kk) {
            float4 a4 = *(const float4*)&qt[kk][ty * 4];
            float4 b4 = *(const float4*)&kt[kk][tx * 4];
            fma16(a4, b4, s);
        }
        __syncthreads();  // done reading kt; reuse it for p
        #pragma unroll
        for (int i = 0; i < 4; ++i) {
            const float p0 = __expf(s[i][0] - m_[i]) * inv_[i];
            const float p1 = __expf(s[i][1] - m_[i]) * inv_[i];
            const float p2 = __expf(s[i][2] - m_[i]) * inv_[i];
            const float p3 = __expf(s[i][3] - m_[i]) * inv_[i];
            const size_t ro = ((size_t)bh * kS + (m0 + ty * 4 + i)) * kS + n0 + tx * 4;
            *(float4*)&out2[ro] = make_float4(p0, p1, p2, p3);
            kt[tx * 4 + 0][ty * 4 + i] = p0;
            kt[tx * 4 + 1][ty * 4 + i] = p1;
            kt[tx * 4 + 2][ty * 4 + i] = p2;
            kt[tx * 4 + 3][ty * 4 + i] = p3;
        }
        __syncthreads();
        #pragma unroll 16
        for (int n = 0; n < 64; ++n) {
            float4 a4 = *(const float4*)&kt[n][ty * 4];  // p[n][row]
            float4 b4 = *(const float4*)&vn[n][tx * 4];  // v[n][d]
            fma16(a4, b4, acc);
        }
    }

    #pragma unroll
    for (int i = 0; i < 4; ++i) {
        const size_t o = ((size_t)b_ * kS + (m0 + ty * 4 + i)) * kD + h_ * kHD + tx * 4;
        *(float4*)&out0[o] = make_float4(acc[i][0], acc[i][1], acc[i][2], acc[i][3]);
    }
}

// ---------------- hedgehog predicted attention (single pass) ----------------
__global__ __launch_bounds__(256) void pred_attn_kernel(
    const float* __restrict__ fq, const float* __restrict__ fk,
    const float* __restrict__ fksum, float* __restrict__ out1)
{
    const int bh = blockIdx.y;
    const int m0 = blockIdx.x * 64;
    const int t = threadIdx.x;
    const int tx = t & 15, ty = t >> 4;
    const int lrow = t >> 2, lc = (t & 3) * 16;

    __shared__ float qt[128][68];  // fq tile transposed: qt[e][row]
    __shared__ float kt[64][68];   // half of fk tile transposed
    __shared__ float fsum[128];

    const float* __restrict__ fqb = fq + (size_t)bh * kS * kF;
    const float* __restrict__ fkb = fk + (size_t)bh * kS * kF;

    #pragma unroll
    for (int half = 0; half < 2; ++half)
        #pragma unroll
        for (int c = 0; c < 16; c += 4) {
            float4 u = *(const float4*)&fqb[(size_t)(m0 + lrow) * kF + half * 64 + lc + c];
            qt[half * 64 + lc + c + 0][lrow] = u.x;
            qt[half * 64 + lc + c + 1][lrow] = u.y;
            qt[half * 64 + lc + c + 2][lrow] = u.z;
            qt[half * 64 + lc + c + 3][lrow] = u.w;
        }
    if (t < 128) fsum[t] = fksum[bh * kF + t];
    __syncthreads();

    float inv_[4];
    {
        float d0 = 0, d1 = 0, d2 = 0, d3 = 0;
        for (int e = 0; e < 128; ++e) {
            const float fs = fsum[e];
            float4 a4 = *(const float4*)&qt[e][ty * 4];
            d0 = fmaf(a4.x, fs, d0); d1 = fmaf(a4.y, fs, d1);
            d2 = fmaf(a4.z, fs, d2); d3 = fmaf(a4.w, fs, d3);
        }
        inv_[0] = 1.f / d0; inv_[1] = 1.f / d1; inv_[2] = 1.f / d2; inv_[3] = 1.f / d3;
    }

    for (int n0 = 0; n0 < kS; n0 += 64) {
        float s[4][4] = {};
        #pragma unroll
        for (int half = 0; half < 2; ++half) {
            __syncthreads();  // previous reads of kt done
            #pragma unroll
            for (int c = 0; c < 16; c += 4) {
                float4 u = *(const float4*)&fkb[(size_t)(n0 + lrow) * kF + half * 64 + lc + c];
                kt[lc + c + 0][lrow] = u.x; kt[lc + c + 1][lrow] = u.y;
                kt[lc + c + 2][lrow] = u.z; kt[lc + c + 3][lrow] = u.w;
            }
            __syncthreads();
            #pragma unroll 16
            for (int kk = 0; kk < 64; ++kk) {
                float4 a4 = *(const float4*)&qt[half * 64 + kk][ty * 4];
                float4 b4 = *(const float4*)&kt[kk][tx * 4];
                fma16(a4, b4, s);
            }
        }
        #pragma unroll
        for (int i = 0; i < 4; ++i) {
            const size_t ro = ((size_t)bh * kS + (m0 + ty * 4 + i)) * kS + n0 + tx * 4;
            *(float4*)&out1[ro] = make_float4(s[i][0] * inv_[i], s[i][1] * inv_[i],
                                              s[i][2] * inv_[i], s[i][3] * inv_[i]);
        }
    }
}

}  // namespace

extern "C" void kernel_launch(void* const* d_in, const int* in_sizes, int n_in,
                              void* d_out, int out_size, void* d_ws, size_t ws_size,
                              hipStream_t stream)
{
    (void)in_sizes; (void)n_in; (void)out_size; (void)ws_size;

    const float* hidden = (const float*)d_in[0];
    const float* Wq = (const float*)d_in[1];
    const float* bq = (const float*)d_in[2];
    const float* Wk = (const float*)d_in[3];
    const float* bk = (const float*)d_in[4];
    const float* Wv = (const float*)d_in[5];
    const float* bv = (const float*)d_in[6];
    const float* Wfq = (const float*)d_in[7];
    const float* bfq = (const float*)d_in[8];
    const float* Wfk = (const float*)d_in[9];
    const float* bfk = (const float*)d_in[10];

    float* out = (float*)d_out;
    float* out0 = out;                                   // outputs   [B,S,D]
    float* out1 = out0 + (size_t)kB * kS * kD;           // pred_attns[B,H,S,S]
    float* out2 = out1 + (size_t)kBH * kS * kS;          // true_attns[B,H,S,S]

    float* ws = (float*)d_ws;
    float* qw  = ws;
    float* kw  = qw  + (size_t)kBH * kS * kHD;
    float* vw  = kw  + (size_t)kBH * kS * kHD;
    float* fqw = vw  + (size_t)kBH * kS * kHD;
    float* fkw = fqw + (size_t)kBH * kS * kF;
    float* part = fkw + (size_t)kBH * kS * kF;           // 24*16*128
    float* fks  = part + (size_t)kBH * 16 * kF;          // 24*128

    qkv_proj_kernel<<<dim3(kB * kS / 64, kD / 64, 3), 256, 0, stream>>>(
        hidden, Wq, bq, Wk, bk, Wv, bv, qw, kw, vw);
    featmap_kernel<<<dim3(kBH * kS / 64, 2), 256, 0, stream>>>(
        qw, kw, Wfq, bfq, Wfk, bfk, fqw, fkw);
    fksum_part_kernel<<<dim3(kBH, 16), 128, 0, stream>>>(fkw, part);
    fksum_red_kernel<<<dim3(kBH), 128, 0, stream>>>(part, fks);
    true_attn_kernel<<<dim3(kS / 64, kBH), 256, 0, stream>>>(qw, kw, vw, out0, out2);
    pred_attn_kernel<<<dim3(kS / 64, kBH), 256, 0, stream>>>(fqw, fkw, fks, out1);
}

// Round 3
// 575.240 us; speedup vs baseline: 2.0904x; 2.0904x over previous
//
#include <hip/hip_runtime.h>
#include <math.h>

namespace {

constexpr int kB = 2, kS = 2048, kD = 768, kH = 12, kHD = 64, kF = 128, kBH = kB * kH;

typedef __attribute__((ext_vector_type(8))) short short8;
typedef __attribute__((ext_vector_type(4))) short short4v;
typedef __attribute__((ext_vector_type(4))) float f32x4;

__device__ __forceinline__ ushort f2bf(float x) {
    union { float f; unsigned u; } v; v.f = x;
    return (ushort)((v.u + 0x7fffu + ((v.u >> 16) & 1u)) >> 16);
}
__device__ __forceinline__ float bf2f(ushort u) {
    union { unsigned u; float f; } v; v.u = ((unsigned)u) << 16; return v.f;
}

__device__ __forceinline__ void fma16(const float4& a4, const float4& b4, float (&acc)[4][4]) {
    const float a[4] = {a4.x, a4.y, a4.z, a4.w};
    const float b[4] = {b4.x, b4.y, b4.z, b4.w};
    #pragma unroll
    for (int i = 0; i < 4; ++i)
        #pragma unroll
        for (int j = 0; j < 4; ++j)
            acc[i][j] = fmaf(a[i], b[j], acc[i][j]);
}

// Stage a 64x64 bf16 tile (rows at srcRow0 + r*rowStride elems) into LDS with
// XOR swizzle: byte = row*128 + (col2 ^ ((row&7)<<4)).
__device__ __forceinline__ void stage64x64(ushort* dst, const ushort* srcRow0,
                                           size_t rowStride, int t) {
    const int row = t >> 2, ce = (t & 3) * 16;
    const ushort* s = srcRow0 + (size_t)row * rowStride + ce;
    uint4 u0 = *(const uint4*)s;
    uint4 u1 = *(const uint4*)(s + 8);
    const int sw = (row & 7) << 4;
    *(uint4*)((char*)dst + row * 128 + ((ce * 2) ^ sw)) = u0;
    *(uint4*)((char*)dst + row * 128 + ((ce * 2 + 16) ^ sw)) = u1;
}

// Stage a 64x128 bf16 tile into LDS, rows 256B, same XOR swizzle.
__device__ __forceinline__ void stage64x128(ushort* dst, const ushort* srcRow0, int t) {
    const int row = t >> 2, ce = (t & 3) * 32;
    const ushort* s = srcRow0 + (size_t)row * kF + ce;
    const int sw = (row & 7) << 4;
    #pragma unroll
    for (int u = 0; u < 4; ++u) {
        uint4 x = *(const uint4*)(s + u * 8);
        *(uint4*)((char*)dst + row * 256 + ((ce * 2 + u * 16) ^ sw)) = x;
    }
}

// ---------------- QKV projection (fp32 compute, bf16 out; v stored transposed) ----------------
__global__ __launch_bounds__(256) void qkv_proj_kernel(
    const float* __restrict__ hidden,
    const float* __restrict__ Wq, const float* __restrict__ bq,
    const float* __restrict__ Wk, const float* __restrict__ bk,
    const float* __restrict__ Wv, const float* __restrict__ bv,
    ushort* __restrict__ qd, ushort* __restrict__ kd, ushort* __restrict__ vTd)
{
    const int which = blockIdx.z;
    const float* __restrict__ W    = (which == 0) ? Wq : (which == 1) ? Wk : Wv;
    const float* __restrict__ bias = (which == 0) ? bq : (which == 1) ? bk : bv;

    const int m0 = blockIdx.x * 64;
    const int n0 = blockIdx.y * 64;
    const int t = threadIdx.x;
    const int tx = t & 15, ty = t >> 4;
    const int lrow = t >> 2;
    const int lc4 = (t & 3) * 4;

    __shared__ float At[16][68];
    __shared__ float Wt[16][68];

    float acc[4][4] = {};

    for (int k0 = 0; k0 < kD; k0 += 16) {
        float4 av = *(const float4*)&hidden[(size_t)(m0 + lrow) * kD + k0 + lc4];
        float4 wv = *(const float4*)&W[(size_t)(n0 + lrow) * kD + k0 + lc4];
        At[lc4 + 0][lrow] = av.x; At[lc4 + 1][lrow] = av.y;
        At[lc4 + 2][lrow] = av.z; At[lc4 + 3][lrow] = av.w;
        Wt[lc4 + 0][lrow] = wv.x; Wt[lc4 + 1][lrow] = wv.y;
        Wt[lc4 + 2][lrow] = wv.z; Wt[lc4 + 3][lrow] = wv.w;
        __syncthreads();
        #pragma unroll
        for (int kk = 0; kk < 16; ++kk) {
            float4 a4 = *(const float4*)&At[kk][ty * 4];
            float4 b4 = *(const float4*)&Wt[kk][tx * 4];
            fma16(a4, b4, acc);
        }
        __syncthreads();
    }

    const int hh = n0 >> 6;
    float4 bv4 = *(const float4*)&bias[n0 + tx * 4];
    const float badd[4] = {bv4.x, bv4.y, bv4.z, bv4.w};

    if (which < 2) {
        ushort* __restrict__ dst = (which == 0) ? qd : kd;
        #pragma unroll
        for (int i = 0; i < 4; ++i) {
            const int m = m0 + ty * 4 + i, b_ = m >> 11, s_ = m & (kS - 1);
            short4v o;
            o[0] = (short)f2bf(acc[i][0] + badd[0]);
            o[1] = (short)f2bf(acc[i][1] + badd[1]);
            o[2] = (short)f2bf(acc[i][2] + badd[2]);
            o[3] = (short)f2bf(acc[i][3] + badd[3]);
            *(short4v*)&dst[((size_t)(b_ * kH + hh) * kS + s_) * kHD + tx * 4] = o;
        }
    } else {
        #pragma unroll
        for (int i = 0; i < 4; ++i) {
            const int m = m0 + ty * 4 + i, b_ = m >> 11, s_ = m & (kS - 1);
            #pragma unroll
            for (int j = 0; j < 4; ++j)
                vTd[((size_t)(b_ * kH + hh) * kHD + tx * 4 + j) * kS + s_] =
                    f2bf(acc[i][j] + badd[j]);
        }
    }
}

// ---------------- hedgehog feature maps (bf16 in / bf16 out) ----------------
__global__ __launch_bounds__(256) void featmap_kernel(
    const ushort* __restrict__ q, const ushort* __restrict__ k,
    const float* __restrict__ Wfq, const float* __restrict__ bfq,
    const float* __restrict__ Wfk, const float* __restrict__ bfk,
    ushort* __restrict__ fq, ushort* __restrict__ fk)
{
    const int zi = blockIdx.y;
    const ushort* __restrict__ src = zi == 0 ? q : k;
    const float* __restrict__ Wf  = zi == 0 ? Wfq : Wfk;
    const float* __restrict__ bf  = zi == 0 ? bfq : bfk;
    ushort* __restrict__ dst      = zi == 0 ? fq : fk;

    const int row0 = blockIdx.x * 64;
    const int t = threadIdx.x;
    const int lane = t & 63, w = t >> 6;
    const int lrow = t >> 2, lc = (t & 3) * 16;

    __shared__ float Wl[64][65];
    __shared__ float ql[64][68];

    #pragma unroll
    for (int c = 0; c < 16; c += 4) {
        float4 u = *(const float4*)&Wf[(size_t)lrow * 64 + lc + c];
        Wl[lrow][lc + c + 0] = u.x; Wl[lrow][lc + c + 1] = u.y;
        Wl[lrow][lc + c + 2] = u.z; Wl[lrow][lc + c + 3] = u.w;
    }
    {
        union { uint4 v; ushort s[8]; } a0, a1;
        a0.v = *(const uint4*)&src[(size_t)(row0 + lrow) * kHD + lc];
        a1.v = *(const uint4*)&src[(size_t)(row0 + lrow) * kHD + lc + 8];
        float4 f;
        f.x = bf2f(a0.s[0]); f.y = bf2f(a0.s[1]); f.z = bf2f(a0.s[2]); f.w = bf2f(a0.s[3]);
        *(float4*)&ql[lrow][lc] = f;
        f.x = bf2f(a0.s[4]); f.y = bf2f(a0.s[5]); f.z = bf2f(a0.s[6]); f.w = bf2f(a0.s[7]);
        *(float4*)&ql[lrow][lc + 4] = f;
        f.x = bf2f(a1.s[0]); f.y = bf2f(a1.s[1]); f.z = bf2f(a1.s[2]); f.w = bf2f(a1.s[3]);
        *(float4*)&ql[lrow][lc + 8] = f;
        f.x = bf2f(a1.s[4]); f.y = bf2f(a1.s[5]); f.z = bf2f(a1.s[6]); f.w = bf2f(a1.s[7]);
        *(float4*)&ql[lrow][lc + 12] = f;
    }
    __syncthreads();

    float wreg[64];
    #pragma unroll
    for (int d = 0; d < 64; ++d) wreg[d] = Wl[lane][d];
    const float bfv = bf[lane];

    for (int rl = 0; rl < 16; ++rl) {
        const int r = w * 16 + rl;
        float y = bfv;
        #pragma unroll
        for (int d4 = 0; d4 < 64; d4 += 4) {
            float4 qv = *(const float4*)&ql[r][d4];
            y = fmaf(qv.x, wreg[d4 + 0], y);
            y = fmaf(qv.y, wreg[d4 + 1], y);
            y = fmaf(qv.z, wreg[d4 + 2], y);
            y = fmaf(qv.w, wreg[d4 + 3], y);
        }
        const size_t base = (size_t)(row0 + r) * kF;
        dst[base + lane]      = f2bf(__expf(y));
        dst[base + 64 + lane] = f2bf(__expf(-y));
    }
}

// ---------------- fk column sums ----------------
__global__ __launch_bounds__(128) void fksum_part_kernel(
    const ushort* __restrict__ fk, float* __restrict__ part)
{
    const int bh = blockIdx.x, g = blockIdx.y, e = threadIdx.x;
    float acc = 0.f;
    const ushort* p = fk + ((size_t)bh * kS + g * 128) * kF + e;
    for (int n = 0; n < 128; ++n) acc += bf2f(p[(size_t)n * kF]);
    part[((size_t)bh * 16 + g) * kF + e] = acc;
}

__global__ __launch_bounds__(128) void fksum_red_kernel(
    const float* __restrict__ part, float* __restrict__ fksum)
{
    const int bh = blockIdx.x, e = threadIdx.x;
    float acc = 0.f;
    for (int g = 0; g < 16; ++g) acc += part[((size_t)bh * 16 + g) * kF + e];
    fksum[bh * kF + e] = acc;
}

// ---------------- softmax attention via MFMA: true_attns + outputs ----------------
__global__ __launch_bounds__(256) void true_attn_kernel(
    const ushort* __restrict__ q, const ushort* __restrict__ k,
    const ushort* __restrict__ vT,
    float* __restrict__ out0, float* __restrict__ out2)
{
    const int bh = blockIdx.y, m0 = blockIdx.x * 64;
    const int t = threadIdx.x, lane = t & 63, w = t >> 6;
    const int g = lane >> 4, ln = lane & 15;

    __shared__ __align__(16) ushort Qs[64 * 64];
    __shared__ __align__(16) ushort Ks[64 * 64];
    __shared__ __align__(16) ushort Vs[64 * 64];   // V^T tile: [d][n]
    __shared__ __align__(16) ushort Ps[64 * 64];   // P tile: [m][n]

    const ushort* __restrict__ qb = q  + (size_t)bh * kS * kHD;
    const ushort* __restrict__ kb = k  + (size_t)bh * kS * kHD;
    const ushort* __restrict__ vb = vT + (size_t)bh * kHD * kS;

    stage64x64(Qs, qb + (size_t)m0 * kHD, kHD, t);
    __syncthreads();

    // hoist Q A-frags (rows 16w+ln)
    short8 aq[2];
    {
        const int row = 16 * w + ln, sw = (row & 7) << 4;
        #pragma unroll
        for (int kc = 0; kc < 2; ++kc)
            aq[kc] = *(const short8*)((const char*)Qs + row * 128 + ((kc * 64 + g * 16) ^ sw));
    }

    // ---- pass 1: row sums of exp(s) (scores are small; no max subtraction) ----
    float zacc[4] = {0.f, 0.f, 0.f, 0.f};
    for (int n0 = 0; n0 < kS; n0 += 64) {
        __syncthreads();
        stage64x64(Ks, kb + (size_t)n0 * kHD, kHD, t);
        __syncthreads();
        #pragma unroll
        for (int nt = 0; nt < 4; ++nt) {
            f32x4 c = {0.f, 0.f, 0.f, 0.f};
            const int rk = nt * 16 + ln, sw = (rk & 7) << 4;
            #pragma unroll
            for (int kc = 0; kc < 2; ++kc) {
                short8 b = *(const short8*)((const char*)Ks + rk * 128 + ((kc * 64 + g * 16) ^ sw));
                c = __builtin_amdgcn_mfma_f32_16x16x32_bf16(aq[kc], b, c, 0, 0, 0);
            }
            #pragma unroll
            for (int r = 0; r < 4; ++r) zacc[r] += __expf(c[r] * 0.125f);
        }
    }
    float invl[4];
    #pragma unroll
    for (int r = 0; r < 4; ++r) {
        float z = zacc[r];
        z += __shfl_xor(z, 1); z += __shfl_xor(z, 2);
        z += __shfl_xor(z, 4); z += __shfl_xor(z, 8);
        invl[r] = 1.f / z;
    }

    // ---- pass 2: probs + PV ----
    f32x4 accv[4];
    #pragma unroll
    for (int dt = 0; dt < 4; ++dt) accv[dt] = (f32x4){0.f, 0.f, 0.f, 0.f};

    for (int n0 = 0; n0 < kS; n0 += 64) {
        __syncthreads();
        stage64x64(Ks, kb + (size_t)n0 * kHD, kHD, t);
        stage64x64(Vs, vb + n0, kS, t);
        __syncthreads();
        #pragma unroll
        for (int nt = 0; nt < 4; ++nt) {
            f32x4 c = {0.f, 0.f, 0.f, 0.f};
            const int rk = nt * 16 + ln, sw = (rk & 7) << 4;
            #pragma unroll
            for (int kc = 0; kc < 2; ++kc) {
                short8 b = *(const short8*)((const char*)Ks + rk * 128 + ((kc * 64 + g * 16) ^ sw));
                c = __builtin_amdgcn_mfma_f32_16x16x32_bf16(aq[kc], b, c, 0, 0, 0);
            }
            #pragma unroll
            for (int r = 0; r < 4; ++r) {
                const int prow = 16 * w + g * 4 + r;
                const float p = __expf(c[r] * 0.125f) * invl[r];
                out2[((size_t)bh * kS + m0 + prow) * kS + n0 + nt * 16 + ln] = p;
                const int pb = prow * 128 + ((2 * (nt * 16 + ln)) ^ ((prow & 7) << 4));
                *(ushort*)((char*)Ps + pb) = f2bf(p);
            }
        }
        __syncthreads();
        // PV: A = P (rows m), B = V^T (rows d)
        const int rowp = 16 * w + ln, swp = (rowp & 7) << 4;
        #pragma unroll
        for (int kc = 0; kc < 2; ++kc) {
            short8 pa = *(const short8*)((const char*)Ps + rowp * 128 + ((kc * 64 + g * 16) ^ swp));
            #pragma unroll
            for (int dt = 0; dt < 4; ++dt) {
                const int rv = dt * 16 + ln, swv = (rv & 7) << 4;
                short8 bv = *(const short8*)((const char*)Vs + rv * 128 + ((kc * 64 + g * 16) ^ swv));
                accv[dt] = __builtin_amdgcn_mfma_f32_16x16x32_bf16(pa, bv, accv[dt], 0, 0, 0);
            }
        }
    }

    const int b_ = bh / kH, h_ = bh % kH;
    #pragma unroll
    for (int dt = 0; dt < 4; ++dt)
        #pragma unroll
        for (int r = 0; r < 4; ++r) {
            const int prow = 16 * w + g * 4 + r;
            out0[((size_t)b_ * kS + m0 + prow) * kD + h_ * kHD + dt * 16 + ln] = accv[dt][r];
        }
}

// ---------------- hedgehog predicted attention via MFMA ----------------
__global__ __launch_bounds__(256) void pred_attn_kernel(
    const ushort* __restrict__ fq, const ushort* __restrict__ fk,
    const float* __restrict__ fksum, float* __restrict__ out1)
{
    const int bh = blockIdx.y, m0 = blockIdx.x * 64;
    const int t = threadIdx.x, lane = t & 63, w = t >> 6;
    const int g = lane >> 4, ln = lane & 15;

    __shared__ __align__(16) ushort Fq[64 * 128];
    __shared__ __align__(16) ushort Fk[64 * 128];
    __shared__ float fsum[128];
    __shared__ float invz[64];

    const ushort* __restrict__ fqb = fq + (size_t)bh * kS * kF;
    const ushort* __restrict__ fkb = fk + (size_t)bh * kS * kF;

    stage64x128(Fq, fqb + (size_t)m0 * kF, t);
    if (t < 128) fsum[t] = fksum[bh * kF + t];
    __syncthreads();

    short8 a[4];
    {
        const int row = 16 * w + ln, sw = (row & 7) << 4;
        #pragma unroll
        for (int kc = 0; kc < 4; ++kc)
            a[kc] = *(const short8*)((const char*)Fq + row * 256 + ((kc * 64 + g * 16) ^ sw));
    }

    // denominator: fq_row . fksum  (row-sum identity), reduce over k-groups
    float den = 0.f;
    #pragma unroll
    for (int kc = 0; kc < 4; ++kc)
        #pragma unroll
        for (int j = 0; j < 8; ++j)
            den += bf2f((ushort)a[kc][j]) * fsum[kc * 32 + g * 8 + j];
    den += __shfl_xor(den, 16);
    den += __shfl_xor(den, 32);
    if (g == 0) invz[16 * w + ln] = 1.f / den;
    __syncthreads();
    float invl[4];
    #pragma unroll
    for (int r = 0; r < 4; ++r) invl[r] = invz[16 * w + g * 4 + r];

    for (int n0 = 0; n0 < kS; n0 += 64) {
        __syncthreads();
        stage64x128(Fk, fkb + (size_t)n0 * kF, t);
        __syncthreads();
        #pragma unroll
        for (int nt = 0; nt < 4; ++nt) {
            f32x4 c = {0.f, 0.f, 0.f, 0.f};
            const int rk = nt * 16 + ln, sw = (rk & 7) << 4;
            #pragma unroll
            for (int kc = 0; kc < 4; ++kc) {
                short8 b = *(const short8*)((const char*)Fk + rk * 256 + ((kc * 64 + g * 16) ^ sw));
                c = __builtin_amdgcn_mfma_f32_16x16x32_bf16(a[kc], b, c, 0, 0, 0);
            }
            #pragma unroll
            for (int r = 0; r < 4; ++r)
                out1[((size_t)bh * kS + m0 + 16 * w + g * 4 + r) * kS + n0 + nt * 16 + ln] =
                    c[r] * invl[r];
        }
    }
}

}  // namespace

extern "C" void kernel_launch(void* const* d_in, const int* in_sizes, int n_in,
                              void* d_out, int out_size, void* d_ws, size_t ws_size,
                              hipStream_t stream)
{
    (void)in_sizes; (void)n_in; (void)out_size; (void)ws_size;

    const float* hidden = (const float*)d_in[0];
    const float* Wq = (const float*)d_in[1];
    const float* bq = (const float*)d_in[2];
    const float* Wk = (const float*)d_in[3];
    const float* bk = (const float*)d_in[4];
    const float* Wv = (const float*)d_in[5];
    const float* bv = (const float*)d_in[6];
    const float* Wfq = (const float*)d_in[7];
    const float* bfq = (const float*)d_in[8];
    const float* Wfk = (const float*)d_in[9];
    const float* bfk = (const float*)d_in[10];

    float* out = (float*)d_out;
    float* out0 = out;                                   // outputs   [B,S,D]
    float* out1 = out0 + (size_t)kB * kS * kD;           // pred_attns[B,H,S,S]
    float* out2 = out1 + (size_t)kBH * kS * kS;          // true_attns[B,H,S,S]

    float* part = (float*)d_ws;                          // [kBH*16*kF]
    float* fks  = part + (size_t)kBH * 16 * kF;          // [kBH*kF]
    ushort* qw  = (ushort*)(fks + (size_t)kBH * kF);
    ushort* kw  = qw  + (size_t)kBH * kS * kHD;
    ushort* vTw = kw  + (size_t)kBH * kS * kHD;
    ushort* fqw = vTw + (size_t)kBH * kS * kHD;
    ushort* fkw = fqw + (size_t)kBH * kS * kF;

    qkv_proj_kernel<<<dim3(kB * kS / 64, kD / 64, 3), 256, 0, stream>>>(
        hidden, Wq, bq, Wk, bk, Wv, bv, qw, kw, vTw);
    featmap_kernel<<<dim3(kBH * kS / 64, 2), 256, 0, stream>>>(
        qw, kw, Wfq, bfq, Wfk, bfk, fqw, fkw);
    fksum_part_kernel<<<dim3(kBH, 16), 128, 0, stream>>>(fkw, part);
    fksum_red_kernel<<<dim3(kBH), 128, 0, stream>>>(part, fks);
    true_attn_kernel<<<dim3(kS / 64, kBH), 256, 0, stream>>>(qw, kw, vTw, out0, out2);
    pred_attn_kernel<<<dim3(kS / 64, kBH), 256, 0, stream>>>(fqw, fkw, fks, out1);
}

// Round 4
// 369.081 us; speedup vs baseline: 3.2581x; 1.5586x over previous
//
#include <hip/hip_runtime.h>
#include <math.h>

namespace {

constexpr int kB = 2, kS = 2048, kD = 768, kH = 12, kHD = 64, kF = 128, kBH = kB * kH;

typedef __attribute__((ext_vector_type(8))) short short8;
typedef __attribute__((ext_vector_type(4))) short short4v;
typedef __attribute__((ext_vector_type(4))) float f32x4;

__device__ __forceinline__ ushort f2bf(float x) {
    union { float f; unsigned u; } v; v.f = x;
    return (ushort)((v.u + 0x7fffu + ((v.u >> 16) & 1u)) >> 16);
}
__device__ __forceinline__ float bf2f(ushort u) {
    union { unsigned u; float f; } v; v.u = ((unsigned)u) << 16; return v.f;
}

__device__ __forceinline__ void fma16(const float4& a4, const float4& b4, float (&acc)[4][4]) {
    const float a[4] = {a4.x, a4.y, a4.z, a4.w};
    const float b[4] = {b4.x, b4.y, b4.z, b4.w};
    #pragma unroll
    for (int i = 0; i < 4; ++i)
        #pragma unroll
        for (int j = 0; j < 4; ++j)
            acc[i][j] = fmaf(a[i], b[j], acc[i][j]);
}

// Stage a 64x64 bf16 tile (rows at srcRow0 + r*rowStride elems) into LDS with
// XOR swizzle: byte = row*128 + (col2 ^ ((row&7)<<4)).
__device__ __forceinline__ void stage64x64(ushort* dst, const ushort* srcRow0,
                                           size_t rowStride, int t) {
    const int row = t >> 2, ce = (t & 3) * 16;
    const ushort* s = srcRow0 + (size_t)row * rowStride + ce;
    uint4 u0 = *(const uint4*)s;
    uint4 u1 = *(const uint4*)(s + 8);
    const int sw = (row & 7) << 4;
    *(uint4*)((char*)dst + row * 128 + ((ce * 2) ^ sw)) = u0;
    *(uint4*)((char*)dst + row * 128 + ((ce * 2 + 16) ^ sw)) = u1;
}

// Stage a 64x128 bf16 tile into LDS, rows 256B, same XOR swizzle.
__device__ __forceinline__ void stage64x128(ushort* dst, const ushort* srcRow0, int t) {
    const int row = t >> 2, ce = (t & 3) * 32;
    const ushort* s = srcRow0 + (size_t)row * kF + ce;
    const int sw = (row & 7) << 4;
    #pragma unroll
    for (int u = 0; u < 4; ++u) {
        uint4 x = *(const uint4*)(s + u * 8);
        *(uint4*)((char*)dst + row * 256 + ((ce * 2 + u * 16) ^ sw)) = x;
    }
}

// ---------------- fp32 -> bf16 casts (hidden + 3 weight matrices) ----------------
__global__ __launch_bounds__(256) void cast_kernel(
    const float* __restrict__ s0, const float* __restrict__ s1,
    const float* __restrict__ s2, const float* __restrict__ s3,
    ushort* __restrict__ d0, ushort* __restrict__ d1,
    ushort* __restrict__ d2, ushort* __restrict__ d3)
{
    const int seg = blockIdx.y;
    const float* src = seg == 0 ? s0 : seg == 1 ? s1 : seg == 2 ? s2 : s3;
    ushort* dst      = seg == 0 ? d0 : seg == 1 ? d1 : seg == 2 ? d2 : d3;
    const int n4 = (seg == 0 ? kB * kS * kD : kD * kD) / 4;
    for (int i = blockIdx.x * 256 + threadIdx.x; i < n4; i += gridDim.x * 256) {
        float4 v = *(const float4*)&src[(size_t)i * 4];
        short4v o;
        o[0] = (short)f2bf(v.x); o[1] = (short)f2bf(v.y);
        o[2] = (short)f2bf(v.z); o[3] = (short)f2bf(v.w);
        *(short4v*)&dst[(size_t)i * 4] = o;
    }
}

// ---------------- QKV projection via MFMA (bf16 in/out; v transposed) ----------------
__global__ __launch_bounds__(256) void qkv_mfma_kernel(
    const ushort* __restrict__ hb,
    const ushort* __restrict__ Wqb, const ushort* __restrict__ Wkb,
    const ushort* __restrict__ Wvb,
    const float* __restrict__ bq, const float* __restrict__ bk,
    const float* __restrict__ bv,
    ushort* __restrict__ qd, ushort* __restrict__ kd, ushort* __restrict__ vTd)
{
    const int which = blockIdx.z;
    const ushort* __restrict__ Wb  = which == 0 ? Wqb : which == 1 ? Wkb : Wvb;
    const float* __restrict__ bias = which == 0 ? bq : which == 1 ? bk : bv;

    const int m0 = blockIdx.x * 128;   // rows of hidden (B*S)
    const int n0 = blockIdx.y * 64;    // output cols (one head)
    const int t = threadIdx.x, lane = t & 63, w = t >> 6;
    const int g = lane >> 4, ln = lane & 15;

    __shared__ __align__(16) ushort As[128 * 64];  // rows 128B, swizzled
    __shared__ __align__(16) ushort Bs[64 * 64];

    f32x4 acc[2][4];
    #pragma unroll
    for (int rs = 0; rs < 2; ++rs)
        #pragma unroll
        for (int nt = 0; nt < 4; ++nt) acc[rs][nt] = (f32x4){0.f, 0.f, 0.f, 0.f};

    for (int k0 = 0; k0 < kD; k0 += 64) {
        __syncthreads();
        #pragma unroll
        for (int u = 0; u < 4; ++u) {   // A: 1024 16B chunks
            const int ci = u * 256 + t, row = ci >> 3, c = ci & 7;
            uint4 x = *(const uint4*)&hb[(size_t)(m0 + row) * kD + k0 + c * 8];
            *(uint4*)((char*)As + row * 128 + ((c * 16) ^ ((row & 7) << 4))) = x;
        }
        #pragma unroll
        for (int u = 0; u < 2; ++u) {   // B: 512 16B chunks
            const int ci = u * 256 + t, row = ci >> 3, c = ci & 7;
            uint4 x = *(const uint4*)&Wb[(size_t)(n0 + row) * kD + k0 + c * 8];
            *(uint4*)((char*)Bs + row * 128 + ((c * 16) ^ ((row & 7) << 4))) = x;
        }
        __syncthreads();

        short8 a[2][2], b[4][2];
        #pragma unroll
        for (int rs = 0; rs < 2; ++rs) {
            const int row = 32 * w + 16 * rs + ln, sw = (row & 7) << 4;
            #pragma unroll
            for (int kc = 0; kc < 2; ++kc)
                a[rs][kc] = *(const short8*)((const char*)As + row * 128 + ((kc * 64 + g * 16) ^ sw));
        }
        #pragma unroll
        for (int nt = 0; nt < 4; ++nt) {
            const int rk = nt * 16 + ln, sw = (rk & 7) << 4;
            #pragma unroll
            for (int kc = 0; kc < 2; ++kc)
                b[nt][kc] = *(const short8*)((const char*)Bs + rk * 128 + ((kc * 64 + g * 16) ^ sw));
        }
        #pragma unroll
        for (int rs = 0; rs < 2; ++rs)
            #pragma unroll
            for (int nt = 0; nt < 4; ++nt)
                #pragma unroll
                for (int kc = 0; kc < 2; ++kc)
                    acc[rs][nt] = __builtin_amdgcn_mfma_f32_16x16x32_bf16(
                        a[rs][kc], b[nt][kc], acc[rs][nt], 0, 0, 0);
    }

    const int hh = n0 >> 6;
    float bvn[4];
    #pragma unroll
    for (int nt = 0; nt < 4; ++nt) bvn[nt] = bias[n0 + nt * 16 + ln];

    if (which < 2) {
        ushort* __restrict__ dst = (which == 0) ? qd : kd;
        #pragma unroll
        for (int rs = 0; rs < 2; ++rs)
            #pragma unroll
            for (int nt = 0; nt < 4; ++nt)
                #pragma unroll
                for (int r = 0; r < 4; ++r) {
                    const int m = m0 + 32 * w + 16 * rs + g * 4 + r;
                    const int b_ = m >> 11, s_ = m & (kS - 1);
                    dst[((size_t)(b_ * kH + hh) * kS + s_) * kHD + nt * 16 + ln] =
                        f2bf(acc[rs][nt][r] + bvn[nt]);
                }
    } else {
        #pragma unroll
        for (int rs = 0; rs < 2; ++rs)
            #pragma unroll
            for (int nt = 0; nt < 4; ++nt) {
                const int m = m0 + 32 * w + 16 * rs + g * 4;
                const int b_ = m >> 11, s_ = m & (kS - 1);
                const int d = nt * 16 + ln;
                short4v o;
                #pragma unroll
                for (int r = 0; r < 4; ++r) o[r] = (short)f2bf(acc[rs][nt][r] + bvn[nt]);
                *(short4v*)&vTd[((size_t)(b_ * kH + hh) * kHD + d) * kS + s_] = o;
            }
    }
}

// ---------------- hedgehog feature maps (bf16 in / bf16 out) ----------------
__global__ __launch_bounds__(256) void featmap_kernel(
    const ushort* __restrict__ q, const ushort* __restrict__ k,
    const float* __restrict__ Wfq, const float* __restrict__ bfq,
    const float* __restrict__ Wfk, const float* __restrict__ bfk,
    ushort* __restrict__ fq, ushort* __restrict__ fk)
{
    const int zi = blockIdx.y;
    const ushort* __restrict__ src = zi == 0 ? q : k;
    const float* __restrict__ Wf  = zi == 0 ? Wfq : Wfk;
    const float* __restrict__ bf  = zi == 0 ? bfq : bfk;
    ushort* __restrict__ dst      = zi == 0 ? fq : fk;

    const int row0 = blockIdx.x * 64;
    const int t = threadIdx.x;
    const int lane = t & 63, w = t >> 6;
    const int lrow = t >> 2, lc = (t & 3) * 16;

    __shared__ float Wl[64][65];
    __shared__ float ql[64][68];

    #pragma unroll
    for (int c = 0; c < 16; c += 4) {
        float4 u = *(const float4*)&Wf[(size_t)lrow * 64 + lc + c];
        Wl[lrow][lc + c + 0] = u.x; Wl[lrow][lc + c + 1] = u.y;
        Wl[lrow][lc + c + 2] = u.z; Wl[lrow][lc + c + 3] = u.w;
    }
    {
        union { uint4 v; ushort s[8]; } a0, a1;
        a0.v = *(const uint4*)&src[(size_t)(row0 + lrow) * kHD + lc];
        a1.v = *(const uint4*)&src[(size_t)(row0 + lrow) * kHD + lc + 8];
        float4 f;
        f.x = bf2f(a0.s[0]); f.y = bf2f(a0.s[1]); f.z = bf2f(a0.s[2]); f.w = bf2f(a0.s[3]);
        *(float4*)&ql[lrow][lc] = f;
        f.x = bf2f(a0.s[4]); f.y = bf2f(a0.s[5]); f.z = bf2f(a0.s[6]); f.w = bf2f(a0.s[7]);
        *(float4*)&ql[lrow][lc + 4] = f;
        f.x = bf2f(a1.s[0]); f.y = bf2f(a1.s[1]); f.z = bf2f(a1.s[2]); f.w = bf2f(a1.s[3]);
        *(float4*)&ql[lrow][lc + 8] = f;
        f.x = bf2f(a1.s[4]); f.y = bf2f(a1.s[5]); f.z = bf2f(a1.s[6]); f.w = bf2f(a1.s[7]);
        *(float4*)&ql[lrow][lc + 12] = f;
    }
    __syncthreads();

    float wreg[64];
    #pragma unroll
    for (int d = 0; d < 64; ++d) wreg[d] = Wl[lane][d];
    const float bfv = bf[lane];

    for (int rl = 0; rl < 16; ++rl) {
        const int r = w * 16 + rl;
        float y = bfv;
        #pragma unroll
        for (int d4 = 0; d4 < 64; d4 += 4) {
            float4 qv = *(const float4*)&ql[r][d4];
            y = fmaf(qv.x, wreg[d4 + 0], y);
            y = fmaf(qv.y, wreg[d4 + 1], y);
            y = fmaf(qv.z, wreg[d4 + 2], y);
            y = fmaf(qv.w, wreg[d4 + 3], y);
        }
        const size_t base = (size_t)(row0 + r) * kF;
        dst[base + lane]      = f2bf(__expf(y));
        dst[base + 64 + lane] = f2bf(__expf(-y));
    }
}

// ---------------- fk column sums ----------------
__global__ __launch_bounds__(128) void fksum_part_kernel(
    const ushort* __restrict__ fk, float* __restrict__ part)
{
    const int bh = blockIdx.x, g = blockIdx.y, e = threadIdx.x;
    float acc = 0.f;
    const ushort* p = fk + ((size_t)bh * kS + g * 128) * kF + e;
    for (int n = 0; n < 128; ++n) acc += bf2f(p[(size_t)n * kF]);
    part[((size_t)bh * 16 + g) * kF + e] = acc;
}

__global__ __launch_bounds__(128) void fksum_red_kernel(
    const float* __restrict__ part, float* __restrict__ fksum)
{
    const int bh = blockIdx.x, e = threadIdx.x;
    float acc = 0.f;
    for (int g = 0; g < 16; ++g) acc += part[((size_t)bh * 16 + g) * kF + e];
    fksum[bh * kF + e] = acc;
}

// ---------------- softmax attention via MFMA: true_attns + outputs ----------------
__global__ __launch_bounds__(256) void true_attn_kernel(
    const ushort* __restrict__ q, const ushort* __restrict__ k,
    const ushort* __restrict__ vT,
    float* __restrict__ out0, float* __restrict__ out2)
{
    // XCD-aware bijective swizzle: group the 32 m-tiles of each bh per XCD.
    const int orig = blockIdx.y * 32 + blockIdx.x;        // 768 blocks
    const int swz  = (orig & 7) * 96 + (orig >> 3);
    const int bh = swz >> 5, m0 = (swz & 31) * 64;

    const int t = threadIdx.x, lane = t & 63, w = t >> 6;
    const int g = lane >> 4, ln = lane & 15;

    __shared__ __align__(16) ushort Qs[64 * 64];
    __shared__ __align__(16) ushort Ks[64 * 64];
    __shared__ __align__(16) ushort Vs[64 * 64];   // V^T tile: [d][n]
    __shared__ __align__(16) ushort Ps[64 * 64];   // P tile: [m][n]

    const ushort* __restrict__ qb = q  + (size_t)bh * kS * kHD;
    const ushort* __restrict__ kb = k  + (size_t)bh * kS * kHD;
    const ushort* __restrict__ vb = vT + (size_t)bh * kHD * kS;

    stage64x64(Qs, qb + (size_t)m0 * kHD, kHD, t);
    __syncthreads();

    short8 aq[2];
    {
        const int row = 16 * w + ln, sw = (row & 7) << 4;
        #pragma unroll
        for (int kc = 0; kc < 2; ++kc)
            aq[kc] = *(const short8*)((const char*)Qs + row * 128 + ((kc * 64 + g * 16) ^ sw));
    }

    // ---- pass 1: row sums of exp(s) ----
    float zacc[4] = {0.f, 0.f, 0.f, 0.f};
    for (int n0 = 0; n0 < kS; n0 += 64) {
        __syncthreads();
        stage64x64(Ks, kb + (size_t)n0 * kHD, kHD, t);
        __syncthreads();
        #pragma unroll
        for (int nt = 0; nt < 4; ++nt) {
            f32x4 c = {0.f, 0.f, 0.f, 0.f};
            const int rk = nt * 16 + ln, sw = (rk & 7) << 4;
            #pragma unroll
            for (int kc = 0; kc < 2; ++kc) {
                short8 b = *(const short8*)((const char*)Ks + rk * 128 + ((kc * 64 + g * 16) ^ sw));
                c = __builtin_amdgcn_mfma_f32_16x16x32_bf16(aq[kc], b, c, 0, 0, 0);
            }
            #pragma unroll
            for (int r = 0; r < 4; ++r) zacc[r] += __expf(c[r] * 0.125f);
        }
    }
    float invl[4];
    #pragma unroll
    for (int r = 0; r < 4; ++r) {
        float z = zacc[r];
        z += __shfl_xor(z, 1); z += __shfl_xor(z, 2);
        z += __shfl_xor(z, 4); z += __shfl_xor(z, 8);
        invl[r] = 1.f / z;
    }

    // ---- pass 2: probs + PV ----
    f32x4 accv[4];
    #pragma unroll
    for (int dt = 0; dt < 4; ++dt) accv[dt] = (f32x4){0.f, 0.f, 0.f, 0.f};

    for (int n0 = 0; n0 < kS; n0 += 64) {
        __syncthreads();
        stage64x64(Ks, kb + (size_t)n0 * kHD, kHD, t);
        stage64x64(Vs, vb + n0, kS, t);
        __syncthreads();
        #pragma unroll
        for (int nt = 0; nt < 4; ++nt) {
            f32x4 c = {0.f, 0.f, 0.f, 0.f};
            const int rk = nt * 16 + ln, sw = (rk & 7) << 4;
            #pragma unroll
            for (int kc = 0; kc < 2; ++kc) {
                short8 b = *(const short8*)((const char*)Ks + rk * 128 + ((kc * 64 + g * 16) ^ sw));
                c = __builtin_amdgcn_mfma_f32_16x16x32_bf16(aq[kc], b, c, 0, 0, 0);
            }
            #pragma unroll
            for (int r = 0; r < 4; ++r) {
                const int prow = 16 * w + g * 4 + r;
                const float p = __expf(c[r] * 0.125f) * invl[r];
                out2[((size_t)bh * kS + m0 + prow) * kS + n0 + nt * 16 + ln] = p;
                const int pb = prow * 128 + ((2 * (nt * 16 + ln)) ^ ((prow & 7) << 4));
                *(ushort*)((char*)Ps + pb) = f2bf(p);
            }
        }
        __syncthreads();
        const int rowp = 16 * w + ln, swp = (rowp & 7) << 4;
        #pragma unroll
        for (int kc = 0; kc < 2; ++kc) {
            short8 pa = *(const short8*)((const char*)Ps + rowp * 128 + ((kc * 64 + g * 16) ^ swp));
            #pragma unroll
            for (int dt = 0; dt < 4; ++dt) {
                const int rv = dt * 16 + ln, swv = (rv & 7) << 4;
                short8 bv = *(const short8*)((const char*)Vs + rv * 128 + ((kc * 64 + g * 16) ^ swv));
                accv[dt] = __builtin_amdgcn_mfma_f32_16x16x32_bf16(pa, bv, accv[dt], 0, 0, 0);
            }
        }
    }

    const int b_ = bh / kH, h_ = bh % kH;
    #pragma unroll
    for (int dt = 0; dt < 4; ++dt)
        #pragma unroll
        for (int r = 0; r < 4; ++r) {
            const int prow = 16 * w + g * 4 + r;
            out0[((size_t)b_ * kS + m0 + prow) * kD + h_ * kHD + dt * 16 + ln] = accv[dt][r];
        }
}

// ---------------- hedgehog predicted attention via MFMA ----------------
__global__ __launch_bounds__(256) void pred_attn_kernel(
    const ushort* __restrict__ fq, const ushort* __restrict__ fk,
    const float* __restrict__ fksum, float* __restrict__ out1)
{
    const int orig = blockIdx.y * 32 + blockIdx.x;        // 768 blocks
    const int swz  = (orig & 7) * 96 + (orig >> 3);
    const int bh = swz >> 5, m0 = (swz & 31) * 64;

    const int t = threadIdx.x, lane = t & 63, w = t >> 6;
    const int g = lane >> 4, ln = lane & 15;

    __shared__ __align__(16) ushort Fq[64 * 128];
    __shared__ __align__(16) ushort Fk[64 * 128];
    __shared__ float fsum[128];
    __shared__ float invz[64];

    const ushort* __restrict__ fqb = fq + (size_t)bh * kS * kF;
    const ushort* __restrict__ fkb = fk + (size_t)bh * kS * kF;

    stage64x128(Fq, fqb + (size_t)m0 * kF, t);
    if (t < 128) fsum[t] = fksum[bh * kF + t];
    __syncthreads();

    short8 a[4];
    {
        const int row = 16 * w + ln, sw = (row & 7) << 4;
        #pragma unroll
        for (int kc = 0; kc < 4; ++kc)
            a[kc] = *(const short8*)((const char*)Fq + row * 256 + ((kc * 64 + g * 16) ^ sw));
    }

    float den = 0.f;
    #pragma unroll
    for (int kc = 0; kc < 4; ++kc)
        #pragma unroll
        for (int j = 0; j < 8; ++j)
            den += bf2f((ushort)a[kc][j]) * fsum[kc * 32 + g * 8 + j];
    den += __shfl_xor(den, 16);
    den += __shfl_xor(den, 32);
    if (g == 0) invz[16 * w + ln] = 1.f / den;
    __syncthreads();
    float invl[4];
    #pragma unroll
    for (int r = 0; r < 4; ++r) invl[r] = invz[16 * w + g * 4 + r];

    for (int n0 = 0; n0 < kS; n0 += 64) {
        __syncthreads();
        stage64x128(Fk, fkb + (size_t)n0 * kF, t);
        __syncthreads();
        #pragma unroll
        for (int nt = 0; nt < 4; ++nt) {
            f32x4 c = {0.f, 0.f, 0.f, 0.f};
            const int rk = nt * 16 + ln, sw = (rk & 7) << 4;
            #pragma unroll
            for (int kc = 0; kc < 4; ++kc) {
                short8 b = *(const short8*)((const char*)Fk + rk * 256 + ((kc * 64 + g * 16) ^ sw));
                c = __builtin_amdgcn_mfma_f32_16x16x32_bf16(a[kc], b, c, 0, 0, 0);
            }
            #pragma unroll
            for (int r = 0; r < 4; ++r)
                out1[((size_t)bh * kS + m0 + 16 * w + g * 4 + r) * kS + n0 + nt * 16 + ln] =
                    c[r] * invl[r];
        }
    }
}

}  // namespace

extern "C" void kernel_launch(void* const* d_in, const int* in_sizes, int n_in,
                              void* d_out, int out_size, void* d_ws, size_t ws_size,
                              hipStream_t stream)
{
    (void)in_sizes; (void)n_in; (void)out_size; (void)ws_size;

    const float* hidden = (const float*)d_in[0];
    const float* Wq = (const float*)d_in[1];
    const float* bq = (const float*)d_in[2];
    const float* Wk = (const float*)d_in[3];
    const float* bk = (const float*)d_in[4];
    const float* Wv = (const float*)d_in[5];
    const float* bv = (const float*)d_in[6];
    const float* Wfq = (const float*)d_in[7];
    const float* bfq = (const float*)d_in[8];
    const float* Wfk = (const float*)d_in[9];
    const float* bfk = (const float*)d_in[10];

    float* out = (float*)d_out;
    float* out0 = out;                                   // outputs   [B,S,D]
    float* out1 = out0 + (size_t)kB * kS * kD;           // pred_attns[B,H,S,S]
    float* out2 = out1 + (size_t)kBH * kS * kS;          // true_attns[B,H,S,S]

    float* part = (float*)d_ws;                          // [kBH*16*kF]
    float* fks  = part + (size_t)kBH * 16 * kF;          // [kBH*kF]
    ushort* hb  = (ushort*)(fks + (size_t)kBH * kF);     // hidden bf16
    ushort* Wqb = hb  + (size_t)kB * kS * kD;
    ushort* Wkb = Wqb + (size_t)kD * kD;
    ushort* Wvb = Wkb + (size_t)kD * kD;
    ushort* qw  = Wvb + (size_t)kD * kD;
    ushort* kw  = qw  + (size_t)kBH * kS * kHD;
    ushort* vTw = kw  + (size_t)kBH * kS * kHD;
    ushort* fqw = vTw + (size_t)kBH * kS * kHD;
    ushort* fkw = fqw + (size_t)kBH * kS * kF;

    cast_kernel<<<dim3(512, 4), 256, 0, stream>>>(
        hidden, Wq, Wk, Wv, hb, Wqb, Wkb, Wvb);
    qkv_mfma_kernel<<<dim3(kB * kS / 128, kD / 64, 3), 256, 0, stream>>>(
        hb, Wqb, Wkb, Wvb, bq, bk, bv, qw, kw, vTw);
    featmap_kernel<<<dim3(kBH * kS / 64, 2), 256, 0, stream>>>(
        qw, kw, Wfq, bfq, Wfk, bfk, fqw, fkw);
    fksum_part_kernel<<<dim3(kBH, 16), 128, 0, stream>>>(fkw, part);
    fksum_red_kernel<<<dim3(kBH), 128, 0, stream>>>(part, fks);
    true_attn_kernel<<<dim3(kS / 64, kBH), 256, 0, stream>>>(qw, kw, vTw, out0, out2);
    pred_attn_kernel<<<dim3(kS / 64, kBH), 256, 0, stream>>>(fqw, fkw, fks, out1);
}

// Round 5
// 317.958 us; speedup vs baseline: 3.7819x; 1.1608x over previous
//
#include <hip/hip_runtime.h>
#include <math.h>

namespace {

constexpr int kB = 2, kS = 2048, kD = 768, kH = 12, kHD = 64, kF = 128, kBH = kB * kH;

typedef __attribute__((ext_vector_type(8))) short short8;
typedef __attribute__((ext_vector_type(4))) short short4v;
typedef __attribute__((ext_vector_type(4))) float f32x4;

__device__ __forceinline__ ushort f2bf(float x) {
    union { float f; unsigned u; } v; v.f = x;
    return (ushort)((v.u + 0x7fffu + ((v.u >> 16) & 1u)) >> 16);
}
__device__ __forceinline__ float bf2f(ushort u) {
    union { unsigned u; float f; } v; v.u = ((unsigned)u) << 16; return v.f;
}

__device__ __forceinline__ void gload16(const ushort* g, void* lds) {
    __builtin_amdgcn_global_load_lds(
        (const __attribute__((address_space(1))) void*)g,
        (__attribute__((address_space(3))) void*)lds, 16, 0, 0);
}

// Async-stage a 64-row x 64-col bf16 tile via global_load_lds.
// LDS layout linear rows of 128B; swizzle applied by pre-permuting the global
// source chunk: LDS[row][c] <- G[row][c ^ (row&7)]  (read side XORs the same).
__device__ __forceinline__ void gstage64x64(ushort* ldsBase, const ushort* g,
                                            size_t strideElems, int w, int lane) {
    #pragma unroll
    for (int j = 0; j < 2; ++j) {
        const int row = 16 * w + 8 * j + (lane >> 3);
        const int chunk = lane & 7;
        const ushort* gp = g + (size_t)row * strideElems + ((chunk ^ (row & 7)) * 8);
        void* lp = (char*)ldsBase + (16 * w + 8 * j) * 128;
        gload16(gp, lp);
    }
}

// Async-stage a 64-row x 128-col bf16 tile (rows 256B, 16 chunks).
__device__ __forceinline__ void gstage64x128(ushort* ldsBase, const ushort* g,
                                             int w, int lane) {
    #pragma unroll
    for (int j = 0; j < 4; ++j) {
        const int row = 16 * w + 4 * j + (lane >> 4);
        const int chunk = lane & 15;
        const ushort* gp = g + (size_t)row * kF + ((chunk ^ (row & 7)) * 8);
        void* lp = (char*)ldsBase + (16 * w + 4 * j) * 256;
        gload16(gp, lp);
    }
}

// Reg-path stage (used outside main loops, where __syncthreads is fine).
__device__ __forceinline__ void stage64x64(ushort* dst, const ushort* srcRow0,
                                           size_t rowStride, int t) {
    const int row = t >> 2, ce = (t & 3) * 16;
    const ushort* s = srcRow0 + (size_t)row * rowStride + ce;
    uint4 u0 = *(const uint4*)s;
    uint4 u1 = *(const uint4*)(s + 8);
    const int sw = (row & 7) << 4;
    *(uint4*)((char*)dst + row * 128 + ((ce * 2) ^ sw)) = u0;
    *(uint4*)((char*)dst + row * 128 + ((ce * 2 + 16) ^ sw)) = u1;
}

__device__ __forceinline__ void stage64x128(ushort* dst, const ushort* srcRow0, int t) {
    const int row = t >> 2, ce = (t & 3) * 32;
    const ushort* s = srcRow0 + (size_t)row * kF + ce;
    const int sw = (row & 7) << 4;
    #pragma unroll
    for (int u = 0; u < 4; ++u) {
        uint4 x = *(const uint4*)(s + u * 8);
        *(uint4*)((char*)dst + row * 256 + ((ce * 2 + u * 16) ^ sw)) = x;
    }
}

// ---------------- fp32 -> bf16 casts ----------------
__global__ __launch_bounds__(256) void cast_kernel(
    const float* __restrict__ s0, const float* __restrict__ s1,
    const float* __restrict__ s2, const float* __restrict__ s3,
    ushort* __restrict__ d0, ushort* __restrict__ d1,
    ushort* __restrict__ d2, ushort* __restrict__ d3)
{
    const int seg = blockIdx.y;
    const float* src = seg == 0 ? s0 : seg == 1 ? s1 : seg == 2 ? s2 : s3;
    ushort* dst      = seg == 0 ? d0 : seg == 1 ? d1 : seg == 2 ? d2 : d3;
    const int n4 = (seg == 0 ? kB * kS * kD : kD * kD) / 4;
    for (int i = blockIdx.x * 256 + threadIdx.x; i < n4; i += gridDim.x * 256) {
        float4 v = *(const float4*)&src[(size_t)i * 4];
        short4v o;
        o[0] = (short)f2bf(v.x); o[1] = (short)f2bf(v.y);
        o[2] = (short)f2bf(v.z); o[3] = (short)f2bf(v.w);
        *(short4v*)&dst[(size_t)i * 4] = o;
    }
}

// ---------------- QKV projection via MFMA ----------------
__global__ __launch_bounds__(256) void qkv_mfma_kernel(
    const ushort* __restrict__ hb,
    const ushort* __restrict__ Wqb, const ushort* __restrict__ Wkb,
    const ushort* __restrict__ Wvb,
    const float* __restrict__ bq, const float* __restrict__ bk,
    const float* __restrict__ bv,
    ushort* __restrict__ qd, ushort* __restrict__ kd, ushort* __restrict__ vTd)
{
    const int which = blockIdx.z;
    const ushort* __restrict__ Wb  = which == 0 ? Wqb : which == 1 ? Wkb : Wvb;
    const float* __restrict__ bias = which == 0 ? bq : which == 1 ? bk : bv;

    const int m0 = blockIdx.x * 128;
    const int n0 = blockIdx.y * 64;
    const int t = threadIdx.x, lane = t & 63, w = t >> 6;
    const int g = lane >> 4, ln = lane & 15;

    __shared__ __align__(16) ushort As[128 * 64];
    __shared__ __align__(16) ushort Bs[64 * 64];

    f32x4 acc[2][4];
    #pragma unroll
    for (int rs = 0; rs < 2; ++rs)
        #pragma unroll
        for (int nt = 0; nt < 4; ++nt) acc[rs][nt] = (f32x4){0.f, 0.f, 0.f, 0.f};

    for (int k0 = 0; k0 < kD; k0 += 64) {
        __syncthreads();
        #pragma unroll
        for (int u = 0; u < 4; ++u) {
            const int ci = u * 256 + t, row = ci >> 3, c = ci & 7;
            uint4 x = *(const uint4*)&hb[(size_t)(m0 + row) * kD + k0 + c * 8];
            *(uint4*)((char*)As + row * 128 + ((c * 16) ^ ((row & 7) << 4))) = x;
        }
        #pragma unroll
        for (int u = 0; u < 2; ++u) {
            const int ci = u * 256 + t, row = ci >> 3, c = ci & 7;
            uint4 x = *(const uint4*)&Wb[(size_t)(n0 + row) * kD + k0 + c * 8];
            *(uint4*)((char*)Bs + row * 128 + ((c * 16) ^ ((row & 7) << 4))) = x;
        }
        __syncthreads();

        short8 a[2][2], b[4][2];
        #pragma unroll
        for (int rs = 0; rs < 2; ++rs) {
            const int row = 32 * w + 16 * rs + ln, sw = (row & 7) << 4;
            #pragma unroll
            for (int kc = 0; kc < 2; ++kc)
                a[rs][kc] = *(const short8*)((const char*)As + row * 128 + ((kc * 64 + g * 16) ^ sw));
        }
        #pragma unroll
        for (int nt = 0; nt < 4; ++nt) {
            const int rk = nt * 16 + ln, sw = (rk & 7) << 4;
            #pragma unroll
            for (int kc = 0; kc < 2; ++kc)
                b[nt][kc] = *(const short8*)((const char*)Bs + rk * 128 + ((kc * 64 + g * 16) ^ sw));
        }
        #pragma unroll
        for (int rs = 0; rs < 2; ++rs)
            #pragma unroll
            for (int nt = 0; nt < 4; ++nt)
                #pragma unroll
                for (int kc = 0; kc < 2; ++kc)
                    acc[rs][nt] = __builtin_amdgcn_mfma_f32_16x16x32_bf16(
                        a[rs][kc], b[nt][kc], acc[rs][nt], 0, 0, 0);
    }

    const int hh = n0 >> 6;
    float bvn[4];
    #pragma unroll
    for (int nt = 0; nt < 4; ++nt) bvn[nt] = bias[n0 + nt * 16 + ln];

    if (which < 2) {
        ushort* __restrict__ dst = (which == 0) ? qd : kd;
        #pragma unroll
        for (int rs = 0; rs < 2; ++rs)
            #pragma unroll
            for (int nt = 0; nt < 4; ++nt)
                #pragma unroll
                for (int r = 0; r < 4; ++r) {
                    const int m = m0 + 32 * w + 16 * rs + g * 4 + r;
                    const int b_ = m >> 11, s_ = m & (kS - 1);
                    dst[((size_t)(b_ * kH + hh) * kS + s_) * kHD + nt * 16 + ln] =
                        f2bf(acc[rs][nt][r] + bvn[nt]);
                }
    } else {
        #pragma unroll
        for (int rs = 0; rs < 2; ++rs)
            #pragma unroll
            for (int nt = 0; nt < 4; ++nt) {
                const int m = m0 + 32 * w + 16 * rs + g * 4;
                const int b_ = m >> 11, s_ = m & (kS - 1);
                const int d = nt * 16 + ln;
                short4v o;
                #pragma unroll
                for (int r = 0; r < 4; ++r) o[r] = (short)f2bf(acc[rs][nt][r] + bvn[nt]);
                *(short4v*)&vTd[((size_t)(b_ * kH + hh) * kHD + d) * kS + s_] = o;
            }
    }
}

// ---------------- hedgehog feature maps ----------------
__global__ __launch_bounds__(256) void featmap_kernel(
    const ushort* __restrict__ q, const ushort* __restrict__ k,
    const float* __restrict__ Wfq, const float* __restrict__ bfq,
    const float* __restrict__ Wfk, const float* __restrict__ bfk,
    ushort* __restrict__ fq, ushort* __restrict__ fk)
{
    const int zi = blockIdx.y;
    const ushort* __restrict__ src = zi == 0 ? q : k;
    const float* __restrict__ Wf  = zi == 0 ? Wfq : Wfk;
    const float* __restrict__ bf  = zi == 0 ? bfq : bfk;
    ushort* __restrict__ dst      = zi == 0 ? fq : fk;

    const int row0 = blockIdx.x * 64;
    const int t = threadIdx.x;
    const int lane = t & 63, w = t >> 6;
    const int lrow = t >> 2, lc = (t & 3) * 16;

    __shared__ float Wl[64][65];
    __shared__ float ql[64][68];

    #pragma unroll
    for (int c = 0; c < 16; c += 4) {
        float4 u = *(const float4*)&Wf[(size_t)lrow * 64 + lc + c];
        Wl[lrow][lc + c + 0] = u.x; Wl[lrow][lc + c + 1] = u.y;
        Wl[lrow][lc + c + 2] = u.z; Wl[lrow][lc + c + 3] = u.w;
    }
    {
        union { uint4 v; ushort s[8]; } a0, a1;
        a0.v = *(const uint4*)&src[(size_t)(row0 + lrow) * kHD + lc];
        a1.v = *(const uint4*)&src[(size_t)(row0 + lrow) * kHD + lc + 8];
        float4 f;
        f.x = bf2f(a0.s[0]); f.y = bf2f(a0.s[1]); f.z = bf2f(a0.s[2]); f.w = bf2f(a0.s[3]);
        *(float4*)&ql[lrow][lc] = f;
        f.x = bf2f(a0.s[4]); f.y = bf2f(a0.s[5]); f.z = bf2f(a0.s[6]); f.w = bf2f(a0.s[7]);
        *(float4*)&ql[lrow][lc + 4] = f;
        f.x = bf2f(a1.s[0]); f.y = bf2f(a1.s[1]); f.z = bf2f(a1.s[2]); f.w = bf2f(a1.s[3]);
        *(float4*)&ql[lrow][lc + 8] = f;
        f.x = bf2f(a1.s[4]); f.y = bf2f(a1.s[5]); f.z = bf2f(a1.s[6]); f.w = bf2f(a1.s[7]);
        *(float4*)&ql[lrow][lc + 12] = f;
    }
    __syncthreads();

    float wreg[64];
    #pragma unroll
    for (int d = 0; d < 64; ++d) wreg[d] = Wl[lane][d];
    const float bfv = bf[lane];

    for (int rl = 0; rl < 16; ++rl) {
        const int r = w * 16 + rl;
        float y = bfv;
        #pragma unroll
        for (int d4 = 0; d4 < 64; d4 += 4) {
            float4 qv = *(const float4*)&ql[r][d4];
            y = fmaf(qv.x, wreg[d4 + 0], y);
            y = fmaf(qv.y, wreg[d4 + 1], y);
            y = fmaf(qv.z, wreg[d4 + 2], y);
            y = fmaf(qv.w, wreg[d4 + 3], y);
        }
        const size_t base = (size_t)(row0 + r) * kF;
        dst[base + lane]      = f2bf(__expf(y));
        dst[base + 64 + lane] = f2bf(__expf(-y));
    }
}

// ---------------- fk column sums ----------------
__global__ __launch_bounds__(128) void fksum_part_kernel(
    const ushort* __restrict__ fk, float* __restrict__ part)
{
    const int bh = blockIdx.x, g = blockIdx.y, e = threadIdx.x;
    float acc = 0.f;
    const ushort* p = fk + ((size_t)bh * kS + g * 128) * kF + e;
    for (int n = 0; n < 128; ++n) acc += bf2f(p[(size_t)n * kF]);
    part[((size_t)bh * 16 + g) * kF + e] = acc;
}

__global__ __launch_bounds__(128) void fksum_red_kernel(
    const float* __restrict__ part, float* __restrict__ fksum)
{
    const int bh = blockIdx.x, e = threadIdx.x;
    float acc = 0.f;
    for (int g = 0; g < 16; ++g) acc += part[((size_t)bh * 16 + g) * kF + e];
    fksum[bh * kF + e] = acc;
}

// ---------------- softmax attention: double-buffered gload_lds pipeline ----------------
__global__ __launch_bounds__(256) void true_attn_kernel(
    const ushort* __restrict__ q, const ushort* __restrict__ k,
    const ushort* __restrict__ vT,
    float* __restrict__ out0, float* __restrict__ out2)
{
    const int orig = blockIdx.y * 32 + blockIdx.x;        // 768 blocks
    const int swz  = (orig & 7) * 96 + (orig >> 3);
    const int bh = swz >> 5, m0 = (swz & 31) * 64;

    const int t = threadIdx.x, lane = t & 63, w = t >> 6;
    const int g = lane >> 4, ln = lane & 15;

    __shared__ __align__(16) ushort Qs[64 * 64];         // 8 KB
    __shared__ __align__(16) ushort Ks[2][64 * 64];      // 16 KB dbuf
    __shared__ __align__(16) ushort Vs[2][64 * 64];      // 16 KB dbuf
    __shared__ __align__(16) ushort Ps[64 * 64];         // 8 KB

    const ushort* __restrict__ qb = q  + (size_t)bh * kS * kHD;
    const ushort* __restrict__ kb = k  + (size_t)bh * kS * kHD;
    const ushort* __restrict__ vb = vT + (size_t)bh * kHD * kS;

    stage64x64(Qs, qb + (size_t)m0 * kHD, kHD, t);
    __syncthreads();

    short8 aq[2];
    {
        const int row = 16 * w + ln, sw = (row & 7) << 4;
        #pragma unroll
        for (int kc = 0; kc < 2; ++kc)
            aq[kc] = *(const short8*)((const char*)Qs + row * 128 + ((kc * 64 + g * 16) ^ sw));
    }

    // ---- pass 1: row sums of exp(s), K double-buffered ----
    gstage64x64(Ks[0], kb, kHD, w, lane);
    float zacc[4] = {0.f, 0.f, 0.f, 0.f};
    for (int tt = 0; tt < 32; ++tt) {
        const int cur = tt & 1;
        if (tt + 1 < 32) {
            gstage64x64(Ks[cur ^ 1], kb + (size_t)(tt + 1) * 64 * kHD, kHD, w, lane);
            asm volatile("s_waitcnt vmcnt(2)" ::: "memory");
        } else {
            asm volatile("s_waitcnt vmcnt(0)" ::: "memory");
        }
        __builtin_amdgcn_sched_barrier(0);
        __builtin_amdgcn_s_barrier();
        const ushort* KsC = Ks[cur];
        #pragma unroll
        for (int nt = 0; nt < 4; ++nt) {
            f32x4 c = {0.f, 0.f, 0.f, 0.f};
            const int rk = nt * 16 + ln, sw = (rk & 7) << 4;
            #pragma unroll
            for (int kc = 0; kc < 2; ++kc) {
                short8 b = *(const short8*)((const char*)KsC + rk * 128 + ((kc * 64 + g * 16) ^ sw));
                c = __builtin_amdgcn_mfma_f32_16x16x32_bf16(aq[kc], b, c, 0, 0, 0);
            }
            #pragma unroll
            for (int r = 0; r < 4; ++r) zacc[r] += __expf(c[r] * 0.125f);
        }
        __builtin_amdgcn_sched_barrier(0);
        __builtin_amdgcn_s_barrier();
    }
    float invl[4];
    #pragma unroll
    for (int r = 0; r < 4; ++r) {
        float z = zacc[r];
        z += __shfl_xor(z, 1); z += __shfl_xor(z, 2);
        z += __shfl_xor(z, 4); z += __shfl_xor(z, 8);
        invl[r] = 1.f / z;
    }

    // ---- pass 2: probs + PV, K/V double-buffered ----
    f32x4 accv[4];
    #pragma unroll
    for (int dt = 0; dt < 4; ++dt) accv[dt] = (f32x4){0.f, 0.f, 0.f, 0.f};

    gstage64x64(Ks[0], kb, kHD, w, lane);
    gstage64x64(Vs[0], vb, kS, w, lane);
    for (int tt = 0; tt < 32; ++tt) {
        const int cur = tt & 1;
        const int n0 = tt * 64;
        if (tt + 1 < 32) {
            gstage64x64(Ks[cur ^ 1], kb + (size_t)(tt + 1) * 64 * kHD, kHD, w, lane);
            gstage64x64(Vs[cur ^ 1], vb + (tt + 1) * 64, kS, w, lane);
            asm volatile("s_waitcnt vmcnt(4)" ::: "memory");
        } else {
            asm volatile("s_waitcnt vmcnt(0)" ::: "memory");
        }
        __builtin_amdgcn_sched_barrier(0);
        __builtin_amdgcn_s_barrier();

        const ushort* KsC = Ks[cur];
        const ushort* VsC = Vs[cur];
        #pragma unroll
        for (int nt = 0; nt < 4; ++nt) {
            f32x4 c = {0.f, 0.f, 0.f, 0.f};
            const int rk = nt * 16 + ln, sw = (rk & 7) << 4;
            #pragma unroll
            for (int kc = 0; kc < 2; ++kc) {
                short8 b = *(const short8*)((const char*)KsC + rk * 128 + ((kc * 64 + g * 16) ^ sw));
                c = __builtin_amdgcn_mfma_f32_16x16x32_bf16(aq[kc], b, c, 0, 0, 0);
            }
            #pragma unroll
            for (int r = 0; r < 4; ++r) {
                const int prow = 16 * w + g * 4 + r;
                const float p = __expf(c[r] * 0.125f) * invl[r];
                out2[((size_t)bh * kS + m0 + prow) * kS + n0 + nt * 16 + ln] = p;
                const int pb = prow * 128 + ((2 * (nt * 16 + ln)) ^ ((prow & 7) << 4));
                *(ushort*)((char*)Ps + pb) = f2bf(p);
            }
        }
        asm volatile("s_waitcnt lgkmcnt(0)" ::: "memory");
        __builtin_amdgcn_sched_barrier(0);
        __builtin_amdgcn_s_barrier();

        const int rowp = 16 * w + ln, swp = (rowp & 7) << 4;
        #pragma unroll
        for (int kc = 0; kc < 2; ++kc) {
            short8 pa = *(const short8*)((const char*)Ps + rowp * 128 + ((kc * 64 + g * 16) ^ swp));
            #pragma unroll
            for (int dt = 0; dt < 4; ++dt) {
                const int rv = dt * 16 + ln, swv = (rv & 7) << 4;
                short8 bv = *(const short8*)((const char*)VsC + rv * 128 + ((kc * 64 + g * 16) ^ swv));
                accv[dt] = __builtin_amdgcn_mfma_f32_16x16x32_bf16(pa, bv, accv[dt], 0, 0, 0);
            }
        }
        __builtin_amdgcn_sched_barrier(0);
        __builtin_amdgcn_s_barrier();
    }

    const int b_ = bh / kH, h_ = bh % kH;
    #pragma unroll
    for (int dt = 0; dt < 4; ++dt)
        #pragma unroll
        for (int r = 0; r < 4; ++r) {
            const int prow = 16 * w + g * 4 + r;
            out0[((size_t)b_ * kS + m0 + prow) * kD + h_ * kHD + dt * 16 + ln] = accv[dt][r];
        }
}

// ---------------- hedgehog predicted attention: double-buffered pipeline ----------------
__global__ __launch_bounds__(256) void pred_attn_kernel(
    const ushort* __restrict__ fq, const ushort* __restrict__ fk,
    const float* __restrict__ fksum, float* __restrict__ out1)
{
    const int orig = blockIdx.y * 32 + blockIdx.x;        // 768 blocks
    const int swz  = (orig & 7) * 96 + (orig >> 3);
    const int bh = swz >> 5, m0 = (swz & 31) * 64;

    const int t = threadIdx.x, lane = t & 63, w = t >> 6;
    const int g = lane >> 4, ln = lane & 15;

    __shared__ __align__(16) ushort Fq[64 * 128];         // 16 KB
    __shared__ __align__(16) ushort Fk[2][64 * 128];      // 32 KB dbuf
    __shared__ float fsum[128];
    __shared__ float invz[64];

    const ushort* __restrict__ fqb = fq + (size_t)bh * kS * kF;
    const ushort* __restrict__ fkb = fk + (size_t)bh * kS * kF;

    stage64x128(Fq, fqb + (size_t)m0 * kF, t);
    if (t < 128) fsum[t] = fksum[bh * kF + t];
    __syncthreads();

    short8 a[4];
    {
        const int row = 16 * w + ln, sw = (row & 7) << 4;
        #pragma unroll
        for (int kc = 0; kc < 4; ++kc)
            a[kc] = *(const short8*)((const char*)Fq + row * 256 + ((kc * 64 + g * 16) ^ sw));
    }

    float den = 0.f;
    #pragma unroll
    for (int kc = 0; kc < 4; ++kc)
        #pragma unroll
        for (int j = 0; j < 8; ++j)
            den += bf2f((ushort)a[kc][j]) * fsum[kc * 32 + g * 8 + j];
    den += __shfl_xor(den, 16);
    den += __shfl_xor(den, 32);
    if (g == 0) invz[16 * w + ln] = 1.f / den;
    __syncthreads();
    float invl[4];
    #pragma unroll
    for (int r = 0; r < 4; ++r) invl[r] = invz[16 * w + g * 4 + r];

    gstage64x128(Fk[0], fkb, w, lane);
    for (int tt = 0; tt < 32; ++tt) {
        const int cur = tt & 1;
        const int n0 = tt * 64;
        if (tt + 1 < 32) {
            gstage64x128(Fk[cur ^ 1], fkb + (size_t)(tt + 1) * 64 * kF, w, lane);
            asm volatile("s_waitcnt vmcnt(4)" ::: "memory");
        } else {
            asm volatile("s_waitcnt vmcnt(0)" ::: "memory");
        }
        __builtin_amdgcn_sched_barrier(0);
        __builtin_amdgcn_s_barrier();

        const ushort* FkC = Fk[cur];
        #pragma unroll
        for (int nt = 0; nt < 4; ++nt) {
            f32x4 c = {0.f, 0.f, 0.f, 0.f};
            const int rk = nt * 16 + ln, sw = (rk & 7) << 4;
            #pragma unroll
            for (int kc = 0; kc < 4; ++kc) {
                short8 b = *(const short8*)((const char*)FkC + rk * 256 + ((kc * 64 + g * 16) ^ sw));
                c = __builtin_amdgcn_mfma_f32_16x16x32_bf16(a[kc], b, c, 0, 0, 0);
            }
            #pragma unroll
            for (int r = 0; r < 4; ++r)
                out1[((size_t)bh * kS + m0 + 16 * w + g * 4 + r) * kS + n0 + nt * 16 + ln] =
                    c[r] * invl[r];
        }
        __builtin_amdgcn_sched_barrier(0);
        __builtin_amdgcn_s_barrier();
    }
}

}  // namespace

extern "C" void kernel_launch(void* const* d_in, const int* in_sizes, int n_in,
                              void* d_out, int out_size, void* d_ws, size_t ws_size,
                              hipStream_t stream)
{
    (void)in_sizes; (void)n_in; (void)out_size; (void)ws_size;

    const float* hidden = (const float*)d_in[0];
    const float* Wq = (const float*)d_in[1];
    const float* bq = (const float*)d_in[2];
    const float* Wk = (const float*)d_in[3];
    const float* bk = (const float*)d_in[4];
    const float* Wv = (const float*)d_in[5];
    const float* bv = (const float*)d_in[6];
    const float* Wfq = (const float*)d_in[7];
    const float* bfq = (const float*)d_in[8];
    const float* Wfk = (const float*)d_in[9];
    const float* bfk = (const float*)d_in[10];

    float* out = (float*)d_out;
    float* out0 = out;                                   // outputs   [B,S,D]
    float* out1 = out0 + (size_t)kB * kS * kD;           // pred_attns[B,H,S,S]
    float* out2 = out1 + (size_t)kBH * kS * kS;          // true_attns[B,H,S,S]

    float* part = (float*)d_ws;                          // [kBH*16*kF]
    float* fks  = part + (size_t)kBH * 16 * kF;          // [kBH*kF]
    ushort* hb  = (ushort*)(fks + (size_t)kBH * kF);     // hidden bf16
    ushort* Wqb = hb  + (size_t)kB * kS * kD;
    ushort* Wkb = Wqb + (size_t)kD * kD;
    ushort* Wvb = Wkb + (size_t)kD * kD;
    ushort* qw  = Wvb + (size_t)kD * kD;
    ushort* kw  = qw  + (size_t)kBH * kS * kHD;
    ushort* vTw = kw  + (size_t)kBH * kS * kHD;
    ushort* fqw = vTw + (size_t)kBH * kS * kHD;
    ushort* fkw = fqw + (size_t)kBH * kS * kF;

    cast_kernel<<<dim3(512, 4), 256, 0, stream>>>(
        hidden, Wq, Wk, Wv, hb, Wqb, Wkb, Wvb);
    qkv_mfma_kernel<<<dim3(kB * kS / 128, kD / 64, 3), 256, 0, stream>>>(
        hb, Wqb, Wkb, Wvb, bq, bk, bv, qw, kw, vTw);
    featmap_kernel<<<dim3(kBH * kS / 64, 2), 256, 0, stream>>>(
        qw, kw, Wfq, bfq, Wfk, bfk, fqw, fkw);
    fksum_part_kernel<<<dim3(kBH, 16), 128, 0, stream>>>(fkw, part);
    fksum_red_kernel<<<dim3(kBH), 128, 0, stream>>>(part, fks);
    true_attn_kernel<<<dim3(kS / 64, kBH), 256, 0, stream>>>(qw, kw, vTw, out0, out2);
    pred_attn_kernel<<<dim3(kS / 64, kBH), 256, 0, stream>>>(fqw, fkw, fks, out1);
}